// Round 2
// baseline (461.912 us; speedup 1.0000x reference)
//
#include <hip/hip_runtime.h>
#include <math.h>

#define TWO_PI 6.283185307179586f
#define C_SQ2 0.70710678118654752f
#define FSTR 2049           // u_ws row stride in float2 (same footprint as r1: 134.3 MB)

__device__ __forceinline__ int PH(int i) { return i + (i >> 3); }  // LDS pad map

__device__ __forceinline__ float2 cadd(float2 a, float2 b){ return make_float2(a.x+b.x, a.y+b.y); }
__device__ __forceinline__ float2 csub(float2 a, float2 b){ return make_float2(a.x-b.x, a.y-b.y); }
__device__ __forceinline__ float2 cmul(float2 a, float2 b){ return make_float2(a.x*b.x - a.y*b.y, a.x*b.y + a.y*b.x); }

template<int SGN>
__device__ __forceinline__ float2 cmulj(float2 a){  // a * (SGN*i)
    return (SGN > 0) ? make_float2(-a.y, a.x) : make_float2(a.y, -a.x);
}

template<int SGN>
__device__ __forceinline__ void dft4(float2 a0, float2 a1, float2 a2, float2 a3,
                                     float2& y0, float2& y1, float2& y2, float2& y3) {
    float2 s0 = cadd(a0, a2), d0 = csub(a0, a2);
    float2 s1 = cadd(a1, a3), d1 = cmulj<SGN>(csub(a1, a3));
    y0 = cadd(s0, s1); y1 = cadd(d0, d1); y2 = csub(s0, s1); y3 = csub(d0, d1);
}

template<int SGN>
__device__ __forceinline__ void dft8(const float2 x[8], float2 y[8]) {
    float2 E0,E1,E2,E3,O0,O1,O2,O3;
    dft4<SGN>(x[0],x[2],x[4],x[6],E0,E1,E2,E3);
    dft4<SGN>(x[1],x[3],x[5],x[7],O0,O1,O2,O3);
    const float sg = (float)SGN;
    float2 t1 = make_float2(C_SQ2*(O1.x - sg*O1.y), C_SQ2*(O1.y + sg*O1.x)); // O1*w8^1
    float2 t2 = cmulj<SGN>(O2);                                              // O2*w8^2
    float2 t3 = make_float2(-C_SQ2*(O3.x + sg*O3.y), C_SQ2*(sg*O3.x - O3.y));// O3*w8^3
    y[0]=cadd(E0,O0); y[4]=csub(E0,O0);
    y[1]=cadd(E1,t1); y[5]=csub(E1,t1);
    y[2]=cadd(E2,t2); y[6]=csub(E2,t2);
    y[3]=cadd(E3,t3); y[7]=csub(E3,t3);
}

// One radix-8 Stockham DIF pass, in-place LDS (PH-padded). Input must be
// barrier-visible on entry. 2 internal barriers. P = 0,1,2; st in [0,256).
template<int SGN, int P>
__device__ __forceinline__ void fft_pass(float2* buf, int st) {
    float2 v[8], y[8];
    #pragma unroll
    for (int r = 0; r < 8; ++r) v[r] = buf[PH(st + 256*r)];
    dft8<SGN>(v, y);
    const int m = 1 << (3*P);
    const int j = st >> (3*P);
    const int q = st & (m-1);
    float th = (float)SGN * (TWO_PI / (float)(2048 >> (3*P))) * (float)j;
    float sw, cw; __sincosf(th, &sw, &cw);
    float2 w1 = make_float2(cw, sw);
    float2 w2 = cmul(w1,w1), w3 = cmul(w1,w2), w4 = cmul(w2,w2),
           w5 = cmul(w2,w3), w6 = cmul(w3,w3), w7 = cmul(w3,w4);
    y[1]=cmul(y[1],w1); y[2]=cmul(y[2],w2); y[3]=cmul(y[3],w3);
    y[4]=cmul(y[4],w4); y[5]=cmul(y[5],w5); y[6]=cmul(y[6],w6); y[7]=cmul(y[7],w7);
    __syncthreads();
    const int base = q + 8*m*j;
    #pragma unroll
    for (int r = 0; r < 8; ++r) buf[PH(base + r*m)] = y[r];
    __syncthreads();
}

// Final radix-4 pass (m=512, l=1, no twiddles); results stay in regs.
// out[i] is the value at logical position st + 256*i.
template<int SGN>
__device__ __forceinline__ void fft_last(const float2* buf, int st, float2 out[8]) {
    #pragma unroll
    for (int h = 0; h < 2; ++h) {
        int q = st + 256*h;
        float2 y0,y1,y2,y3;
        dft4<SGN>(buf[PH(q)], buf[PH(q+512)], buf[PH(q+1024)], buf[PH(q+1536)],
                  y0, y1, y2, y3);
        out[0*2+h] = y0; out[1*2+h] = y1; out[2*2+h] = y2; out[3*2+h] = y3;
    }
}

// K1: one block per (b,c) row. rfft (radix-8 Stockham) + L*K Jacobi per bin,
// u spectra -> ws, layout [(b*8+k)*16 + c][f], stride FSTR.
__global__ void __launch_bounds__(256)
k_fwd(const float* __restrict__ x, const float* __restrict__ log_alpha,
      const float* __restrict__ raw_tau, const float* __restrict__ raw_omega,
      float2* __restrict__ u_ws)
{
    __shared__ float2 buf[2304];
    __shared__ float s_2a[64], s_tau[8], s_om[8];
    const int st = threadIdx.x;
    const int b = blockIdx.x >> 4, c = blockIdx.x & 15;

    if (st < 64) s_2a[st] = 2.0f * __expf(log_alpha[st]);
    if (st < 8)  s_tau[st] = log1pf(__expf(raw_tau[st]));
    if (st < 8)  s_om[st]  = 0.5f / (1.0f + __expf(-raw_omega[st]));

    // stage packed row: z[n] = x[2n] + i x[2n+1]
    const float* xr = x + (size_t)b * 4096 * 16 + c;
    #pragma unroll
    for (int i = 0; i < 8; ++i) {
        int n = st + 256*i;
        float e = xr[(size_t)(2*n)   * 16];
        float o = xr[(size_t)(2*n+1) * 16];
        buf[PH(n)] = make_float2(e, o);
    }
    __syncthreads();

    fft_pass<-1,0>(buf, st);
    fft_pass<-1,1>(buf, st);
    fft_pass<-1,2>(buf, st);
    float2 zz[8];
    fft_last<-1>(buf, st, zz);
    #pragma unroll
    for (int i = 0; i < 8; ++i) buf[PH(st + 256*i)] = zz[i];  // own slots, race-free
    __syncthreads();

    const size_t sb = (size_t)(b*128 + c);
    for (int f = st; f < 2049; f += 256) {
        float2 Zk = buf[PH(f & 2047)];
        float2 Zm = buf[PH((2048 - f) & 2047)];
        float2 E = make_float2(0.5f*(Zk.x+Zm.x), 0.5f*(Zk.y-Zm.y));
        float2 D = make_float2(0.5f*(Zk.x-Zm.x), 0.5f*(Zk.y+Zm.y));
        float2 O = make_float2(D.y, -D.x);
        float ang = -(TWO_PI/4096.f) * (float)f;
        float sw, cw; __sincosf(ang, &sw, &cw);
        float fhx = E.x + cw*O.x - sw*O.y;
        float fhy = E.y + cw*O.y + sw*O.x;

        float freq = (float)f * (0.5f/2048.f);
        float dd[8];
        #pragma unroll
        for (int k = 0; k < 8; ++k) { float d = freq - s_om[k]; dd[k] = d*d; }

        float2 u[8];
        #pragma unroll
        for (int k = 0; k < 8; ++k) u[k] = make_float2(0.f, 0.f);
        float lamx = 0.f, lamy = 0.f;

        #pragma unroll
        for (int l = 0; l < 8; ++l) {
            float usx = 0.f, usy = 0.f;
            #pragma unroll
            for (int k = 0; k < 8; ++k) { usx += u[k].x; usy += u[k].y; }
            float bx = fhx - usx + 0.5f*lamx;
            float by = fhy - usy + 0.5f*lamy;
            float sx = 0.f, sy = 0.f;
            #pragma unroll
            for (int k = 0; k < 8; ++k) {
                float den = fmaf(s_2a[l*8+k], dd[k], 1.0f);
                float r = __builtin_amdgcn_rcpf(den);
                float ux = (bx + u[k].x) * r;
                float uy = (by + u[k].y) * r;
                u[k].x = ux; u[k].y = uy;
                sx += ux; sy += uy;
            }
            lamx += s_tau[l] * (fhx - sx);
            lamy += s_tau[l] * (fhy - sy);
        }

        #pragma unroll
        for (int k = 0; k < 8; ++k)
            u_ws[(sb + (size_t)k*16) * FSTR + f] = u[k];
    }
}

// K2: one block per (b,k); 4 subgroups x 256 thr, each does 4 channels
// sequentially (c = 4*sg + ci). irfft via radix-8 Stockham; outputs held in
// regs and stored as dense float4s at the end (full 64B line per out row).
__global__ void __launch_bounds__(1024)
k_inv(const float2* __restrict__ u_ws, float* __restrict__ out)
{
    __shared__ float2 lds[4][2304];
    const int tid = threadIdx.x;
    const int sg = tid >> 8, st = tid & 255;
    const int bk = blockIdx.x;
    float2* buf = lds[sg];

    float2 val[4][8];

    #pragma unroll
    for (int ci = 0; ci < 4; ++ci) {
        const int cc = 4*sg + ci;
        const float2* sp = u_ws + (size_t)(bk*16 + cc) * FSTR;
        #pragma unroll
        for (int i = 0; i < 8; ++i) buf[PH(st + 256*i)] = sp[st + 256*i];
        if (st == 0) buf[2303] = sp[2048];   // Nyquist
        __syncthreads();

        // repack: Z[j] = (E + i*W^j D) / M   (read pairs -> regs -> barrier -> write)
        float2 zreg[8];
        #pragma unroll
        for (int i = 0; i < 8; ++i) {
            int j2 = st + 256*i;
            float2 Xj = buf[PH(j2)];
            float2 Xm = (j2 == 0) ? buf[2303] : buf[PH(2048 - j2)];
            float2 E = make_float2(0.5f*(Xj.x+Xm.x), 0.5f*(Xj.y-Xm.y));
            float2 D = make_float2(0.5f*(Xj.x-Xm.x), 0.5f*(Xj.y+Xm.y));
            float ang = (TWO_PI/4096.f) * (float)j2;
            float sw, cw; __sincosf(ang, &sw, &cw);
            float2 O = make_float2(cw*D.x - sw*D.y, cw*D.y + sw*D.x);
            const float sc = 1.0f/2048.f;
            zreg[i] = make_float2((E.x - O.y)*sc, (E.y + O.x)*sc);
        }
        __syncthreads();
        #pragma unroll
        for (int i = 0; i < 8; ++i) buf[PH(st + 256*i)] = zreg[i];
        __syncthreads();

        fft_pass<1,0>(buf, st);
        fft_pass<1,1>(buf, st);
        fft_pass<1,2>(buf, st);
        fft_last<1>(buf, st, val[ci]);
        __syncthreads();   // all fft_last reads done before next ci's load
    }

    const size_t ob = (size_t)bk * 4096 * 16;
    #pragma unroll
    for (int i = 0; i < 8; ++i) {
        int n = st + 256*i;            // complex sample n -> times 2n, 2n+1
        float4 A = make_float4(val[0][i].x, val[1][i].x, val[2][i].x, val[3][i].x);
        float4 B = make_float4(val[0][i].y, val[1][i].y, val[2][i].y, val[3][i].y);
        *(float4*)(out + ob + (size_t)(2*n)  *16 + 4*sg) = A;
        *(float4*)(out + ob + (size_t)(2*n+1)*16 + 4*sg) = B;
    }
}

extern "C" void kernel_launch(void* const* d_in, const int* in_sizes, int n_in,
                              void* d_out, int out_size, void* d_ws, size_t ws_size,
                              hipStream_t stream) {
    const float* x         = (const float*)d_in[0];
    const float* log_alpha = (const float*)d_in[1];
    const float* raw_tau   = (const float*)d_in[2];
    const float* raw_omega = (const float*)d_in[3];
    float* out = (float*)d_out;
    float2* u_ws = (float2*)d_ws;    // 8192 * 2049 * 8 B = 134.3 MB

    k_fwd<<<dim3(1024), dim3(256), 0, stream>>>(x, log_alpha, raw_tau, raw_omega, u_ws);
    k_inv<<<dim3(512), dim3(1024), 0, stream>>>(u_ws, out);
}

// Round 3
// 428.103 us; speedup vs baseline: 1.0790x; 1.0790x over previous
//
#include <hip/hip_runtime.h>
#include <math.h>

#define TWO_PI 6.283185307179586f
#define C_SQ2 0.70710678118654752f
#define FSTR 2056           // u_ws row stride in float2; 2056*8 = 16448 B = 64B-aligned rows

__device__ __forceinline__ int PH(int i) { return i + (i >> 3); }  // LDS pad map

__device__ __forceinline__ float2 cadd(float2 a, float2 b){ return make_float2(a.x+b.x, a.y+b.y); }
__device__ __forceinline__ float2 csub(float2 a, float2 b){ return make_float2(a.x-b.x, a.y-b.y); }
__device__ __forceinline__ float2 cmul(float2 a, float2 b){ return make_float2(a.x*b.x - a.y*b.y, a.x*b.y + a.y*b.x); }

template<int SGN>
__device__ __forceinline__ float2 cmulj(float2 a){  // a * (SGN*i)
    return (SGN > 0) ? make_float2(-a.y, a.x) : make_float2(a.y, -a.x);
}

template<int SGN>
__device__ __forceinline__ void dft4(float2 a0, float2 a1, float2 a2, float2 a3,
                                     float2& y0, float2& y1, float2& y2, float2& y3) {
    float2 s0 = cadd(a0, a2), d0 = csub(a0, a2);
    float2 s1 = cadd(a1, a3), d1 = cmulj<SGN>(csub(a1, a3));
    y0 = cadd(s0, s1); y1 = cadd(d0, d1); y2 = csub(s0, s1); y3 = csub(d0, d1);
}

template<int SGN>
__device__ __forceinline__ void dft8(const float2 x[8], float2 y[8]) {
    float2 E0,E1,E2,E3,O0,O1,O2,O3;
    dft4<SGN>(x[0],x[2],x[4],x[6],E0,E1,E2,E3);
    dft4<SGN>(x[1],x[3],x[5],x[7],O0,O1,O2,O3);
    const float sg = (float)SGN;
    float2 t1 = make_float2(C_SQ2*(O1.x - sg*O1.y), C_SQ2*(O1.y + sg*O1.x)); // O1*w8^1
    float2 t2 = cmulj<SGN>(O2);                                              // O2*w8^2
    float2 t3 = make_float2(-C_SQ2*(O3.x + sg*O3.y), C_SQ2*(sg*O3.x - O3.y));// O3*w8^3
    y[0]=cadd(E0,O0); y[4]=csub(E0,O0);
    y[1]=cadd(E1,t1); y[5]=csub(E1,t1);
    y[2]=cadd(E2,t2); y[6]=csub(E2,t2);
    y[3]=cadd(E3,t3); y[7]=csub(E3,t3);
}

// One radix-8 Stockham DIF pass, in-place LDS (PH-padded). 2 internal barriers.
template<int SGN, int P>
__device__ __forceinline__ void fft_pass(float2* buf, int st) {
    float2 v[8], y[8];
    #pragma unroll
    for (int r = 0; r < 8; ++r) v[r] = buf[PH(st + 256*r)];
    dft8<SGN>(v, y);
    const int m = 1 << (3*P);
    const int j = st >> (3*P);
    const int q = st & (m-1);
    float th = (float)SGN * (TWO_PI / (float)(2048 >> (3*P))) * (float)j;
    float sw, cw; __sincosf(th, &sw, &cw);
    float2 w1 = make_float2(cw, sw);
    float2 w2 = cmul(w1,w1), w3 = cmul(w1,w2), w4 = cmul(w2,w2),
           w5 = cmul(w2,w3), w6 = cmul(w3,w3), w7 = cmul(w3,w4);
    y[1]=cmul(y[1],w1); y[2]=cmul(y[2],w2); y[3]=cmul(y[3],w3);
    y[4]=cmul(y[4],w4); y[5]=cmul(y[5],w5); y[6]=cmul(y[6],w6); y[7]=cmul(y[7],w7);
    __syncthreads();
    const int base = q + 8*m*j;
    #pragma unroll
    for (int r = 0; r < 8; ++r) buf[PH(base + r*m)] = y[r];
    __syncthreads();
}

// Final radix-4 pass (m=512, no twiddles); results stay in regs.
// out[i] = value at logical position st + 256*i.
template<int SGN>
__device__ __forceinline__ void fft_last(const float2* buf, int st, float2 out[8]) {
    #pragma unroll
    for (int h = 0; h < 2; ++h) {
        int q = st + 256*h;
        float2 y0,y1,y2,y3;
        dft4<SGN>(buf[PH(q)], buf[PH(q+512)], buf[PH(q+1024)], buf[PH(q+1536)],
                  y0, y1, y2, y3);
        out[0*2+h] = y0; out[1*2+h] = y1; out[2*2+h] = y2; out[3*2+h] = y3;
    }
}

// K1: one block per (b,c) row. rfft (radix-8 Stockham) + L*K Jacobi per bin,
// u spectra -> ws, row index (b*8+k)*16 + c, stride FSTR.
__global__ void __launch_bounds__(256)
k_fwd(const float* __restrict__ x, const float* __restrict__ log_alpha,
      const float* __restrict__ raw_tau, const float* __restrict__ raw_omega,
      float2* __restrict__ u_ws)
{
    __shared__ float2 buf[2304];
    __shared__ float s_2a[64], s_tau[8], s_om[8];
    const int st = threadIdx.x;
    const int b = blockIdx.x >> 4, c = blockIdx.x & 15;

    if (st < 64) s_2a[st] = 2.0f * __expf(log_alpha[st]);
    if (st < 8)  s_tau[st] = log1pf(__expf(raw_tau[st]));
    if (st < 8)  s_om[st]  = 0.5f / (1.0f + __expf(-raw_omega[st]));

    // stage packed row: z[n] = x[2n] + i x[2n+1]
    const float* xr = x + (size_t)b * 4096 * 16 + c;
    #pragma unroll
    for (int i = 0; i < 8; ++i) {
        int n = st + 256*i;
        float e = xr[(size_t)(2*n)   * 16];
        float o = xr[(size_t)(2*n+1) * 16];
        buf[PH(n)] = make_float2(e, o);
    }
    __syncthreads();

    fft_pass<-1,0>(buf, st);
    fft_pass<-1,1>(buf, st);
    fft_pass<-1,2>(buf, st);
    float2 zz[8];
    fft_last<-1>(buf, st, zz);
    #pragma unroll
    for (int i = 0; i < 8; ++i) buf[PH(st + 256*i)] = zz[i];  // own slots, race-free
    __syncthreads();

    const size_t sb = (size_t)(b*128 + c);
    for (int f = st; f < 2049; f += 256) {
        float2 Zk = buf[PH(f & 2047)];
        float2 Zm = buf[PH((2048 - f) & 2047)];
        float2 E = make_float2(0.5f*(Zk.x+Zm.x), 0.5f*(Zk.y-Zm.y));
        float2 D = make_float2(0.5f*(Zk.x-Zm.x), 0.5f*(Zk.y+Zm.y));
        float2 O = make_float2(D.y, -D.x);
        float ang = -(TWO_PI/4096.f) * (float)f;
        float sw, cw; __sincosf(ang, &sw, &cw);
        float fhx = E.x + cw*O.x - sw*O.y;
        float fhy = E.y + cw*O.y + sw*O.x;

        float freq = (float)f * (0.5f/2048.f);
        float dd[8];
        #pragma unroll
        for (int k = 0; k < 8; ++k) { float d = freq - s_om[k]; dd[k] = d*d; }

        float2 u[8];
        #pragma unroll
        for (int k = 0; k < 8; ++k) u[k] = make_float2(0.f, 0.f);
        float lamx = 0.f, lamy = 0.f;

        #pragma unroll
        for (int l = 0; l < 8; ++l) {
            float usx = 0.f, usy = 0.f;
            #pragma unroll
            for (int k = 0; k < 8; ++k) { usx += u[k].x; usy += u[k].y; }
            float bx = fhx - usx + 0.5f*lamx;
            float by = fhy - usy + 0.5f*lamy;
            float sx = 0.f, sy = 0.f;
            #pragma unroll
            for (int k = 0; k < 8; ++k) {
                float den = fmaf(s_2a[l*8+k], dd[k], 1.0f);
                float r = __builtin_amdgcn_rcpf(den);
                float ux = (bx + u[k].x) * r;
                float uy = (by + u[k].y) * r;
                u[k].x = ux; u[k].y = uy;
                sx += ux; sy += uy;
            }
            lamx += s_tau[l] * (fhx - sx);
            lamy += s_tau[l] * (fhy - sy);
        }

        #pragma unroll
        for (int k = 0; k < 8; ++k)
            u_ws[(sb + (size_t)k*16) * FSTR + f] = u[k];
    }
}

// K2: one block per (b,k); 4 subgroups x 256 thr, each does 4 channels
// sequentially (c = 4*sg + ci). irfft via radix-8 Stockham. Output goes
// through a chunked LDS transpose so every wave store is a full 64B line:
// a 4-lane group (cg=0..3) covers out[t][0..15] exactly.
__global__ void __launch_bounds__(1024)
k_inv(const float2* __restrict__ u_ws, float* __restrict__ out)
{
    __shared__ float2 lds[4][2304];
    const int tid = threadIdx.x;
    const int sg = tid >> 8, st = tid & 255;
    const int bk = blockIdx.x;
    float2* buf = lds[sg];

    float2 val[4][8];

    #pragma unroll
    for (int ci = 0; ci < 4; ++ci) {
        const int cc = 4*sg + ci;
        const float2* sp = u_ws + (size_t)(bk*16 + cc) * FSTR;
        #pragma unroll
        for (int i = 0; i < 8; ++i) buf[PH(st + 256*i)] = sp[st + 256*i];
        if (st == 0) buf[2303] = sp[2048];   // Nyquist
        __syncthreads();

        // repack: Z[j] = (E + i*W^j D) / M
        float2 zreg[8];
        #pragma unroll
        for (int i = 0; i < 8; ++i) {
            int j2 = st + 256*i;
            float2 Xj = buf[PH(j2)];
            float2 Xm = (j2 == 0) ? buf[2303] : buf[PH(2048 - j2)];
            float2 E = make_float2(0.5f*(Xj.x+Xm.x), 0.5f*(Xj.y-Xm.y));
            float2 D = make_float2(0.5f*(Xj.x-Xm.x), 0.5f*(Xj.y+Xm.y));
            float ang = (TWO_PI/4096.f) * (float)j2;
            float sw, cw; __sincosf(ang, &sw, &cw);
            float2 O = make_float2(cw*D.x - sw*D.y, cw*D.y + sw*D.x);
            const float sc = 1.0f/2048.f;
            zreg[i] = make_float2((E.x - O.y)*sc, (E.y + O.x)*sc);
        }
        __syncthreads();
        #pragma unroll
        for (int i = 0; i < 8; ++i) buf[PH(st + 256*i)] = zreg[i];
        __syncthreads();

        fft_pass<1,0>(buf, st);
        fft_pass<1,1>(buf, st);
        fft_pass<1,2>(buf, st);
        fft_last<1>(buf, st, val[ci]);
        __syncthreads();   // all fft_last reads done before buffers are reused
    }

    // Chunked transpose + full-line stores. tr[c][n_local], pad 260.
    float2 (*tr)[260] = reinterpret_cast<float2(*)[260]>(&lds[0][0]);  // 33.3 KB
    const size_t ob = (size_t)bk * 4096 * 16;
    const int nl = tid >> 2, cg = tid & 3;
    #pragma unroll
    for (int i = 0; i < 8; ++i) {
        #pragma unroll
        for (int ci = 0; ci < 4; ++ci) tr[4*sg + ci][st] = val[ci][i];
        __syncthreads();
        float2 a0 = tr[4*cg + 0][nl];
        float2 a1 = tr[4*cg + 1][nl];
        float2 a2 = tr[4*cg + 2][nl];
        float2 a3 = tr[4*cg + 3][nl];
        int n = 256*i + nl;            // complex sample -> times 2n, 2n+1
        *(float4*)(out + ob + (size_t)(2*n)  *16 + 4*cg) = make_float4(a0.x,a1.x,a2.x,a3.x);
        *(float4*)(out + ob + (size_t)(2*n+1)*16 + 4*cg) = make_float4(a0.y,a1.y,a2.y,a3.y);
        __syncthreads();               // chunk reads done before next chunk's writes
    }
}

extern "C" void kernel_launch(void* const* d_in, const int* in_sizes, int n_in,
                              void* d_out, int out_size, void* d_ws, size_t ws_size,
                              hipStream_t stream) {
    const float* x         = (const float*)d_in[0];
    const float* log_alpha = (const float*)d_in[1];
    const float* raw_tau   = (const float*)d_in[2];
    const float* raw_omega = (const float*)d_in[3];
    float* out = (float*)d_out;
    float2* u_ws = (float2*)d_ws;    // 8192 * 2056 * 8 B = 134.7 MB

    k_fwd<<<dim3(1024), dim3(256), 0, stream>>>(x, log_alpha, raw_tau, raw_omega, u_ws);
    k_inv<<<dim3(512), dim3(1024), 0, stream>>>(u_ws, out);
}

// Round 4
// 415.138 us; speedup vs baseline: 1.1127x; 1.0312x over previous
//
#include <hip/hip_runtime.h>
#include <hip/hip_fp16.h>
#include <math.h>

#define TWO_PI 6.283185307179586f
#define C_SQ2 0.70710678118654752f
#define FSTR_H 2064                 // u_ws row stride in half2 (8256 B, 64B-aligned)
#define XT_OFF_FLOATS (83886080/4)  // xT at ws + 80 MB (u_ws uses 67.6 MB)

__device__ __forceinline__ int PH(int i) { return i + (i >> 3); }  // LDS pad map

__device__ __forceinline__ float2 cadd(float2 a, float2 b){ return make_float2(a.x+b.x, a.y+b.y); }
__device__ __forceinline__ float2 csub(float2 a, float2 b){ return make_float2(a.x-b.x, a.y-b.y); }
__device__ __forceinline__ float2 cmul(float2 a, float2 b){ return make_float2(a.x*b.x - a.y*b.y, a.x*b.y + a.y*b.x); }

template<int SGN>
__device__ __forceinline__ float2 cmulj(float2 a){  // a * (SGN*i)
    return (SGN > 0) ? make_float2(-a.y, a.x) : make_float2(a.y, -a.x);
}

template<int SGN>
__device__ __forceinline__ void dft4(float2 a0, float2 a1, float2 a2, float2 a3,
                                     float2& y0, float2& y1, float2& y2, float2& y3) {
    float2 s0 = cadd(a0, a2), d0 = csub(a0, a2);
    float2 s1 = cadd(a1, a3), d1 = cmulj<SGN>(csub(a1, a3));
    y0 = cadd(s0, s1); y1 = cadd(d0, d1); y2 = csub(s0, s1); y3 = csub(d0, d1);
}

template<int SGN>
__device__ __forceinline__ void dft8(const float2 x[8], float2 y[8]) {
    float2 E0,E1,E2,E3,O0,O1,O2,O3;
    dft4<SGN>(x[0],x[2],x[4],x[6],E0,E1,E2,E3);
    dft4<SGN>(x[1],x[3],x[5],x[7],O0,O1,O2,O3);
    const float sg = (float)SGN;
    float2 t1 = make_float2(C_SQ2*(O1.x - sg*O1.y), C_SQ2*(O1.y + sg*O1.x));
    float2 t2 = cmulj<SGN>(O2);
    float2 t3 = make_float2(-C_SQ2*(O3.x + sg*O3.y), C_SQ2*(sg*O3.x - O3.y));
    y[0]=cadd(E0,O0); y[4]=csub(E0,O0);
    y[1]=cadd(E1,t1); y[5]=csub(E1,t1);
    y[2]=cadd(E2,t2); y[6]=csub(E2,t2);
    y[3]=cadd(E3,t3); y[7]=csub(E3,t3);
}

// Twiddle+scatter tail shared by all radix-8 passes. 2 barriers.
template<int SGN, int P>
__device__ __forceinline__ void pass_tail(float2* buf, int st, float2 y[8]) {
    const int m = 1 << (3*P);
    const int j = st >> (3*P);
    const int q = st & (m-1);
    float th = (float)SGN * (TWO_PI / (float)(2048 >> (3*P))) * (float)j;
    float sw, cw; __sincosf(th, &sw, &cw);
    float2 w1 = make_float2(cw, sw);
    float2 w2 = cmul(w1,w1), w3 = cmul(w1,w2), w4 = cmul(w2,w2),
           w5 = cmul(w2,w3), w6 = cmul(w3,w3), w7 = cmul(w3,w4);
    y[1]=cmul(y[1],w1); y[2]=cmul(y[2],w2); y[3]=cmul(y[3],w3);
    y[4]=cmul(y[4],w4); y[5]=cmul(y[5],w5); y[6]=cmul(y[6],w6); y[7]=cmul(y[7],w7);
    __syncthreads();
    const int base = q + 8*m*j;
    #pragma unroll
    for (int r = 0; r < 8; ++r) buf[PH(base + r*m)] = y[r];
    __syncthreads();
}

template<int SGN, int P>
__device__ __forceinline__ void fft_pass(float2* buf, int st) {
    float2 v[8], y[8];
    #pragma unroll
    for (int r = 0; r < 8; ++r) v[r] = buf[PH(st + 256*r)];
    dft8<SGN>(v, y);
    pass_tail<SGN,P>(buf, st, y);
}

// k_inv pass 0 with the irfft repack fused into the read:
// buf holds the half-spectrum X at PH(0..2047), Nyquist at slot 2303.
__device__ __forceinline__ void pass0_repack(float2* buf, int st) {
    float2 v[8], y[8];
    #pragma unroll
    for (int r = 0; r < 8; ++r) {
        int p = st + 256*r;
        float2 Xj = buf[PH(p)];
        float2 Xm = (p == 0) ? buf[2303] : buf[PH(2048 - p)];
        float2 E = make_float2(0.5f*(Xj.x+Xm.x), 0.5f*(Xj.y-Xm.y));
        float2 D = make_float2(0.5f*(Xj.x-Xm.x), 0.5f*(Xj.y+Xm.y));
        float ang = (TWO_PI/4096.f) * (float)p;
        float sw, cw; __sincosf(ang, &sw, &cw);
        float2 O = make_float2(cw*D.x - sw*D.y, cw*D.y + sw*D.x);
        const float sc = 1.0f/2048.f;
        v[r] = make_float2((E.x - O.y)*sc, (E.y + O.x)*sc);
    }
    dft8<1>(v, y);
    pass_tail<1,0>(buf, st, y);
}

// Final radix-4 pass (m=512, no twiddles); results stay in regs.
template<int SGN>
__device__ __forceinline__ void fft_last(const float2* buf, int st, float2 out[8]) {
    #pragma unroll
    for (int h = 0; h < 2; ++h) {
        int q = st + 256*h;
        float2 y0,y1,y2,y3;
        dft4<SGN>(buf[PH(q)], buf[PH(q+512)], buf[PH(q+1024)], buf[PH(q+1536)],
                  y0, y1, y2, y3);
        out[0*2+h] = y0; out[1*2+h] = y1; out[2*2+h] = y2; out[3*2+h] = y3;
    }
}

// K0: x (B,T,C) -> xT (B,C,T), coalesced both sides via LDS tile.
__global__ void __launch_bounds__(256)
k_tr(const float* __restrict__ x, float* __restrict__ xT)
{
    __shared__ float tile[16][260];
    const int tid = threadIdx.x;
    const int b = blockIdx.x >> 4, t0 = (blockIdx.x & 15) * 256;

    const float4* src = (const float4*)(x + ((size_t)b*4096 + t0 + tid)*16);
    float4 v0 = src[0], v1 = src[1], v2 = src[2], v3 = src[3];
    tile[ 0][tid]=v0.x; tile[ 1][tid]=v0.y; tile[ 2][tid]=v0.z; tile[ 3][tid]=v0.w;
    tile[ 4][tid]=v1.x; tile[ 5][tid]=v1.y; tile[ 6][tid]=v1.z; tile[ 7][tid]=v1.w;
    tile[ 8][tid]=v2.x; tile[ 9][tid]=v2.y; tile[10][tid]=v2.z; tile[11][tid]=v2.w;
    tile[12][tid]=v3.x; tile[13][tid]=v3.y; tile[14][tid]=v3.z; tile[15][tid]=v3.w;
    __syncthreads();

    const int cb = (tid >> 6) * 4, j = (tid & 63) * 4;
    #pragma unroll
    for (int cc = 0; cc < 4; ++cc) {
        int c = cb + cc;
        float4 w = make_float4(tile[c][j], tile[c][j+1], tile[c][j+2], tile[c][j+3]);
        *(float4*)(xT + ((size_t)(b*16 + c))*4096 + t0 + j) = w;
    }
}

// K1: one block per (b,c). Coalesced xT row -> rfft -> L*K Jacobi -> fp16 spectra.
__global__ void __launch_bounds__(256)
k_fwd(const float* __restrict__ xT, const float* __restrict__ log_alpha,
      const float* __restrict__ raw_tau, const float* __restrict__ raw_omega,
      __half2* __restrict__ u_ws)
{
    __shared__ float2 buf[2304];
    __shared__ float s_2a[64], s_tau[8], s_om[8];
    const int st = threadIdx.x;
    const int b = blockIdx.x >> 4, c = blockIdx.x & 15;

    if (st < 64) s_2a[st] = 2.0f * __expf(log_alpha[st]);
    if (st < 8)  s_tau[st] = log1pf(__expf(raw_tau[st]));
    if (st < 8)  s_om[st]  = 0.5f / (1.0f + __expf(-raw_omega[st]));

    // z[n] = x[2n] + i x[2n+1]  == the float2 at index n of the coalesced row
    const float2* xr = (const float2*)(xT + (size_t)(b*16 + c) * 4096);
    #pragma unroll
    for (int i = 0; i < 8; ++i) {
        int n = st + 256*i;
        buf[PH(n)] = xr[n];
    }
    __syncthreads();

    fft_pass<-1,0>(buf, st);
    fft_pass<-1,1>(buf, st);
    fft_pass<-1,2>(buf, st);
    float2 zz[8];
    fft_last<-1>(buf, st, zz);
    #pragma unroll
    for (int i = 0; i < 8; ++i) buf[PH(st + 256*i)] = zz[i];
    __syncthreads();

    const size_t sb = (size_t)(b*128 + c);
    for (int f = st; f < 2049; f += 256) {
        float2 Zk = buf[PH(f & 2047)];
        float2 Zm = buf[PH((2048 - f) & 2047)];
        float2 E = make_float2(0.5f*(Zk.x+Zm.x), 0.5f*(Zk.y-Zm.y));
        float2 D = make_float2(0.5f*(Zk.x-Zm.x), 0.5f*(Zk.y+Zm.y));
        float2 O = make_float2(D.y, -D.x);
        float ang = -(TWO_PI/4096.f) * (float)f;
        float sw, cw; __sincosf(ang, &sw, &cw);
        float fhx = E.x + cw*O.x - sw*O.y;
        float fhy = E.y + cw*O.y + sw*O.x;

        float freq = (float)f * (0.5f/2048.f);
        float dd[8];
        #pragma unroll
        for (int k = 0; k < 8; ++k) { float d = freq - s_om[k]; dd[k] = d*d; }

        float2 u[8];
        #pragma unroll
        for (int k = 0; k < 8; ++k) u[k] = make_float2(0.f, 0.f);
        float lamx = 0.f, lamy = 0.f;

        #pragma unroll
        for (int l = 0; l < 8; ++l) {
            float usx = 0.f, usy = 0.f;
            #pragma unroll
            for (int k = 0; k < 8; ++k) { usx += u[k].x; usy += u[k].y; }
            float bx = fhx - usx + 0.5f*lamx;
            float by = fhy - usy + 0.5f*lamy;
            float sx = 0.f, sy = 0.f;
            #pragma unroll
            for (int k = 0; k < 8; ++k) {
                float den = fmaf(s_2a[l*8+k], dd[k], 1.0f);
                float r = __builtin_amdgcn_rcpf(den);
                float ux = (bx + u[k].x) * r;
                float uy = (by + u[k].y) * r;
                u[k].x = ux; u[k].y = uy;
                sx += ux; sy += uy;
            }
            lamx += s_tau[l] * (fhx - sx);
            lamy += s_tau[l] * (fhy - sy);
        }

        #pragma unroll
        for (int k = 0; k < 8; ++k)
            u_ws[(sb + (size_t)k*16) * FSTR_H + f] = __float22half2_rn(u[k]);
    }
}

// K2: one block per (b,k); 4 subgroups x 256 thr, 4 channels each (c = 4*sg+ci).
// fp16 spectra in, repack fused into FFT pass 0, register prefetch of next row,
// chunked LDS transpose so every out store is a full 64B line.
__global__ void __launch_bounds__(1024)
k_inv(const __half2* __restrict__ u_ws, float* __restrict__ out)
{
    __shared__ float2 lds[4][2304];
    const int tid = threadIdx.x;
    const int sg = tid >> 8, st = tid & 255;
    const int bk = blockIdx.x;
    float2* buf = lds[sg];

    float2 val[4][8];
    __half2 pre[8], preNyq;

    const __half2* sp0 = u_ws + (size_t)(bk*16 + 4*sg) * FSTR_H;
    #pragma unroll
    for (int i = 0; i < 8; ++i) pre[i] = sp0[st + 256*i];
    if (st == 0) preNyq = sp0[2048];

    #pragma unroll
    for (int ci = 0; ci < 4; ++ci) {
        // commit prefetched row to LDS as X
        #pragma unroll
        for (int i = 0; i < 8; ++i) buf[PH(st + 256*i)] = __half22float2(pre[i]);
        if (st == 0) buf[2303] = __half22float2(preNyq);
        __syncthreads();

        // issue next row's loads (consumed at next iteration's commit)
        if (ci < 3) {
            const __half2* spn = sp0 + (size_t)(ci + 1) * FSTR_H;
            #pragma unroll
            for (int i = 0; i < 8; ++i) pre[i] = spn[st + 256*i];
            if (st == 0) preNyq = spn[2048];
        }

        pass0_repack(buf, st);          // repack + radix-8 pass 0
        fft_pass<1,1>(buf, st);
        fft_pass<1,2>(buf, st);
        fft_last<1>(buf, st, val[ci]);
        __syncthreads();                // fft_last reads done before buffer reuse
    }

    // Chunked transpose + full-line stores. tr[c][n_local], pad 260.
    float2 (*tr)[260] = reinterpret_cast<float2(*)[260]>(&lds[0][0]);
    const size_t ob = (size_t)bk * 4096 * 16;
    const int nl = tid >> 2, cg = tid & 3;
    #pragma unroll
    for (int i = 0; i < 8; ++i) {
        #pragma unroll
        for (int ci = 0; ci < 4; ++ci) tr[4*sg + ci][st] = val[ci][i];
        __syncthreads();
        float2 a0 = tr[4*cg + 0][nl];
        float2 a1 = tr[4*cg + 1][nl];
        float2 a2 = tr[4*cg + 2][nl];
        float2 a3 = tr[4*cg + 3][nl];
        int n = 256*i + nl;
        *(float4*)(out + ob + (size_t)(2*n)  *16 + 4*cg) = make_float4(a0.x,a1.x,a2.x,a3.x);
        *(float4*)(out + ob + (size_t)(2*n+1)*16 + 4*cg) = make_float4(a0.y,a1.y,a2.y,a3.y);
        __syncthreads();
    }
}

extern "C" void kernel_launch(void* const* d_in, const int* in_sizes, int n_in,
                              void* d_out, int out_size, void* d_ws, size_t ws_size,
                              hipStream_t stream) {
    const float* x         = (const float*)d_in[0];
    const float* log_alpha = (const float*)d_in[1];
    const float* raw_tau   = (const float*)d_in[2];
    const float* raw_omega = (const float*)d_in[3];
    float* out = (float*)d_out;

    __half2* u_ws = (__half2*)d_ws;                       // 8192*2064*4 B = 67.6 MB
    float*   xT   = (float*)d_ws + XT_OFF_FLOATS;         // 16.8 MB at +80 MB

    k_tr <<<dim3(1024), dim3(256),  0, stream>>>(x, xT);
    k_fwd<<<dim3(1024), dim3(256),  0, stream>>>(xT, log_alpha, raw_tau, raw_omega, u_ws);
    k_inv<<<dim3(512),  dim3(1024), 0, stream>>>(u_ws, out);
}

// Round 5
// 403.792 us; speedup vs baseline: 1.1439x; 1.0281x over previous
//
#include <hip/hip_runtime.h>
#include <hip/hip_fp16.h>
#include <math.h>

#define TWO_PI 6.283185307179586f
#define C_SQ2 0.70710678118654752f
#define FSTR_H 2064                 // u_ws row stride in half2 (8256 B, 64B-aligned)
#define XT_OFF_FLOATS (83886080/4)  // xT at ws + 80 MB (u_ws uses 67.6 MB)

__device__ __forceinline__ int PH(int i) { return i + (i >> 3); }  // LDS pad map

__device__ __forceinline__ float2 cadd(float2 a, float2 b){ return make_float2(a.x+b.x, a.y+b.y); }
__device__ __forceinline__ float2 csub(float2 a, float2 b){ return make_float2(a.x-b.x, a.y-b.y); }
__device__ __forceinline__ float2 cmul(float2 a, float2 b){ return make_float2(a.x*b.x - a.y*b.y, a.x*b.y + a.y*b.x); }

template<int SGN>
__device__ __forceinline__ float2 cmulj(float2 a){  // a * (SGN*i)
    return (SGN > 0) ? make_float2(-a.y, a.x) : make_float2(a.y, -a.x);
}

template<int SGN>
__device__ __forceinline__ void dft4(float2 a0, float2 a1, float2 a2, float2 a3,
                                     float2& y0, float2& y1, float2& y2, float2& y3) {
    float2 s0 = cadd(a0, a2), d0 = csub(a0, a2);
    float2 s1 = cadd(a1, a3), d1 = cmulj<SGN>(csub(a1, a3));
    y0 = cadd(s0, s1); y1 = cadd(d0, d1); y2 = csub(s0, s1); y3 = csub(d0, d1);
}

template<int SGN>
__device__ __forceinline__ void dft8(const float2 x[8], float2 y[8]) {
    float2 E0,E1,E2,E3,O0,O1,O2,O3;
    dft4<SGN>(x[0],x[2],x[4],x[6],E0,E1,E2,E3);
    dft4<SGN>(x[1],x[3],x[5],x[7],O0,O1,O2,O3);
    const float sg = (float)SGN;
    float2 t1 = make_float2(C_SQ2*(O1.x - sg*O1.y), C_SQ2*(O1.y + sg*O1.x));
    float2 t2 = cmulj<SGN>(O2);
    float2 t3 = make_float2(-C_SQ2*(O3.x + sg*O3.y), C_SQ2*(sg*O3.x - O3.y));
    y[0]=cadd(E0,O0); y[4]=csub(E0,O0);
    y[1]=cadd(E1,t1); y[5]=csub(E1,t1);
    y[2]=cadd(E2,t2); y[6]=csub(E2,t2);
    y[3]=cadd(E3,t3); y[7]=csub(E3,t3);
}

// Twiddle+scatter tail shared by all radix-8 passes. 2 barriers.
template<int SGN, int P>
__device__ __forceinline__ void pass_tail(float2* buf, int st, float2 y[8]) {
    const int m = 1 << (3*P);
    const int j = st >> (3*P);
    const int q = st & (m-1);
    float th = (float)SGN * (TWO_PI / (float)(2048 >> (3*P))) * (float)j;
    float sw, cw; __sincosf(th, &sw, &cw);
    float2 w1 = make_float2(cw, sw);
    float2 w2 = cmul(w1,w1), w3 = cmul(w1,w2), w4 = cmul(w2,w2),
           w5 = cmul(w2,w3), w6 = cmul(w3,w3), w7 = cmul(w3,w4);
    y[1]=cmul(y[1],w1); y[2]=cmul(y[2],w2); y[3]=cmul(y[3],w3);
    y[4]=cmul(y[4],w4); y[5]=cmul(y[5],w5); y[6]=cmul(y[6],w6); y[7]=cmul(y[7],w7);
    __syncthreads();
    const int base = q + 8*m*j;
    #pragma unroll
    for (int r = 0; r < 8; ++r) buf[PH(base + r*m)] = y[r];
    __syncthreads();
}

template<int SGN, int P>
__device__ __forceinline__ void fft_pass(float2* buf, int st) {
    float2 v[8], y[8];
    #pragma unroll
    for (int r = 0; r < 8; ++r) v[r] = buf[PH(st + 256*r)];
    dft8<SGN>(v, y);
    pass_tail<SGN,P>(buf, st, y);
}

// k_inv pass 0 with the irfft repack fused into the read:
// buf holds the half-spectrum X at PH(0..2047), Nyquist at slot 2303.
__device__ __forceinline__ void pass0_repack(float2* buf, int st) {
    float2 v[8], y[8];
    #pragma unroll
    for (int r = 0; r < 8; ++r) {
        int p = st + 256*r;
        float2 Xj = buf[PH(p)];
        float2 Xm = (p == 0) ? buf[2303] : buf[PH(2048 - p)];
        float2 E = make_float2(0.5f*(Xj.x+Xm.x), 0.5f*(Xj.y-Xm.y));
        float2 D = make_float2(0.5f*(Xj.x-Xm.x), 0.5f*(Xj.y+Xm.y));
        float ang = (TWO_PI/4096.f) * (float)p;
        float sw, cw; __sincosf(ang, &sw, &cw);
        float2 O = make_float2(cw*D.x - sw*D.y, cw*D.y + sw*D.x);
        const float sc = 1.0f/2048.f;
        v[r] = make_float2((E.x - O.y)*sc, (E.y + O.x)*sc);
    }
    dft8<1>(v, y);
    pass_tail<1,0>(buf, st, y);
}

// Final radix-4 pass (m=512, no twiddles); results stay in regs.
// val[i] = complex sample at logical position st + 256*i (verified: 2r+h form
// collapses to 256*i).
template<int SGN>
__device__ __forceinline__ void fft_last(const float2* buf, int st, float2 out[8]) {
    #pragma unroll
    for (int h = 0; h < 2; ++h) {
        int q = st + 256*h;
        float2 y0,y1,y2,y3;
        dft4<SGN>(buf[PH(q)], buf[PH(q+512)], buf[PH(q+1024)], buf[PH(q+1536)],
                  y0, y1, y2, y3);
        out[0*2+h] = y0; out[1*2+h] = y1; out[2*2+h] = y2; out[3*2+h] = y3;
    }
}

// K0: x (B,T,C) -> xT (B,C,T), coalesced both sides via LDS tile.
__global__ void __launch_bounds__(256)
k_tr(const float* __restrict__ x, float* __restrict__ xT)
{
    __shared__ float tile[16][260];
    const int tid = threadIdx.x;
    const int b = blockIdx.x >> 4, t0 = (blockIdx.x & 15) * 256;

    const float4* src = (const float4*)(x + ((size_t)b*4096 + t0 + tid)*16);
    float4 v0 = src[0], v1 = src[1], v2 = src[2], v3 = src[3];
    tile[ 0][tid]=v0.x; tile[ 1][tid]=v0.y; tile[ 2][tid]=v0.z; tile[ 3][tid]=v0.w;
    tile[ 4][tid]=v1.x; tile[ 5][tid]=v1.y; tile[ 6][tid]=v1.z; tile[ 7][tid]=v1.w;
    tile[ 8][tid]=v2.x; tile[ 9][tid]=v2.y; tile[10][tid]=v2.z; tile[11][tid]=v2.w;
    tile[12][tid]=v3.x; tile[13][tid]=v3.y; tile[14][tid]=v3.z; tile[15][tid]=v3.w;
    __syncthreads();

    const int cb = (tid >> 6) * 4, j = (tid & 63) * 4;
    #pragma unroll
    for (int cc = 0; cc < 4; ++cc) {
        int c = cb + cc;
        float4 w = make_float4(tile[c][j], tile[c][j+1], tile[c][j+2], tile[c][j+3]);
        *(float4*)(xT + ((size_t)(b*16 + c))*4096 + t0 + j) = w;
    }
}

// K1: one block per (b,c). Coalesced xT row -> rfft -> L*K Jacobi -> fp16 spectra.
__global__ void __launch_bounds__(256)
k_fwd(const float* __restrict__ xT, const float* __restrict__ log_alpha,
      const float* __restrict__ raw_tau, const float* __restrict__ raw_omega,
      __half2* __restrict__ u_ws)
{
    __shared__ float2 buf[2304];
    __shared__ float s_2a[64], s_tau[8], s_om[8];
    const int st = threadIdx.x;
    const int b = blockIdx.x >> 4, c = blockIdx.x & 15;

    if (st < 64) s_2a[st] = 2.0f * __expf(log_alpha[st]);
    if (st < 8)  s_tau[st] = log1pf(__expf(raw_tau[st]));
    if (st < 8)  s_om[st]  = 0.5f / (1.0f + __expf(-raw_omega[st]));

    const float2* xr = (const float2*)(xT + (size_t)(b*16 + c) * 4096);
    #pragma unroll
    for (int i = 0; i < 8; ++i) {
        int n = st + 256*i;
        buf[PH(n)] = xr[n];
    }
    __syncthreads();

    fft_pass<-1,0>(buf, st);
    fft_pass<-1,1>(buf, st);
    fft_pass<-1,2>(buf, st);
    float2 zz[8];
    fft_last<-1>(buf, st, zz);
    #pragma unroll
    for (int i = 0; i < 8; ++i) buf[PH(st + 256*i)] = zz[i];
    __syncthreads();

    const size_t sb = (size_t)(b*128 + c);
    for (int f = st; f < 2049; f += 256) {
        float2 Zk = buf[PH(f & 2047)];
        float2 Zm = buf[PH((2048 - f) & 2047)];
        float2 E = make_float2(0.5f*(Zk.x+Zm.x), 0.5f*(Zk.y-Zm.y));
        float2 D = make_float2(0.5f*(Zk.x-Zm.x), 0.5f*(Zk.y+Zm.y));
        float2 O = make_float2(D.y, -D.x);
        float ang = -(TWO_PI/4096.f) * (float)f;
        float sw, cw; __sincosf(ang, &sw, &cw);
        float fhx = E.x + cw*O.x - sw*O.y;
        float fhy = E.y + cw*O.y + sw*O.x;

        float freq = (float)f * (0.5f/2048.f);
        float dd[8];
        #pragma unroll
        for (int k = 0; k < 8; ++k) { float d = freq - s_om[k]; dd[k] = d*d; }

        float2 u[8];
        #pragma unroll
        for (int k = 0; k < 8; ++k) u[k] = make_float2(0.f, 0.f);
        float lamx = 0.f, lamy = 0.f;

        #pragma unroll
        for (int l = 0; l < 8; ++l) {
            float usx = 0.f, usy = 0.f;
            #pragma unroll
            for (int k = 0; k < 8; ++k) { usx += u[k].x; usy += u[k].y; }
            float bx = fhx - usx + 0.5f*lamx;
            float by = fhy - usy + 0.5f*lamy;
            float sx = 0.f, sy = 0.f;
            #pragma unroll
            for (int k = 0; k < 8; ++k) {
                float den = fmaf(s_2a[l*8+k], dd[k], 1.0f);
                float r = __builtin_amdgcn_rcpf(den);
                float ux = (bx + u[k].x) * r;
                float uy = (by + u[k].y) * r;
                u[k].x = ux; u[k].y = uy;
                sx += ux; sy += uy;
            }
            lamx += s_tau[l] * (fhx - sx);
            lamy += s_tau[l] * (fhy - sy);
        }

        #pragma unroll
        for (int k = 0; k < 8; ++k)
            u_ws[(sb + (size_t)k*16) * FSTR_H + f] = __float22half2_rn(u[k]);
    }
}

// K2: one block per (b,k); 4 subgroups x 256 thr, 4 channels each (c = 4*sg+ci).
// fp16 spectra in, repack fused into FFT pass 0, register prefetch of next row.
// Tail: 2-slot LDS transpose chunks; in chunk h, subgroup h emits 256 B
// contiguous of out per thread (r1's known-clean store signature).
__global__ void __launch_bounds__(1024)
k_inv(const __half2* __restrict__ u_ws, float* __restrict__ out)
{
    __shared__ float2 lds[4][2304];   // 73728 B
    const int tid = threadIdx.x;
    const int sg = tid >> 8, st = tid & 255;
    const int bk = blockIdx.x;
    float2* buf = lds[sg];

    float2 val[4][8];
    __half2 pre[8], preNyq;

    const __half2* sp0 = u_ws + (size_t)(bk*16 + 4*sg) * FSTR_H;
    #pragma unroll
    for (int i = 0; i < 8; ++i) pre[i] = sp0[st + 256*i];
    if (st == 0) preNyq = sp0[2048];

    #pragma unroll
    for (int ci = 0; ci < 4; ++ci) {
        #pragma unroll
        for (int i = 0; i < 8; ++i) buf[PH(st + 256*i)] = __half22float2(pre[i]);
        if (st == 0) buf[2303] = __half22float2(preNyq);
        __syncthreads();

        if (ci < 3) {
            const __half2* spn = sp0 + (size_t)(ci + 1) * FSTR_H;
            #pragma unroll
            for (int i = 0; i < 8; ++i) pre[i] = spn[st + 256*i];
            if (st == 0) preNyq = spn[2048];
        }

        pass0_repack(buf, st);
        fft_pass<1,1>(buf, st);
        fft_pass<1,2>(buf, st);
        fft_last<1>(buf, st, val[ci]);
        __syncthreads();   // everyone done reading buf before tr clobbers lds
    }

    // Tail. tr[c][n_local], 2 slots per chunk (512 t values), stride 516.
    // tr spans 66 KB of lds (aliases all bufs) — ci-loop's final barrier covers it.
    float2 (*tr)[516] = reinterpret_cast<float2(*)[516]>(&lds[0][0]);
    const size_t ob = (size_t)bk * 4096 * 16;
    #pragma unroll
    for (int h = 0; h < 4; ++h) {
        #pragma unroll
        for (int ci = 0; ci < 4; ++ci) {
            tr[4*sg + ci][st]       = val[ci][2*h];     // n_local = st
            tr[4*sg + ci][st + 256] = val[ci][2*h + 1]; // n_local = st+256
        }
        __syncthreads();
        if (sg == h) {
            // thread q owns out[t0 .. t0+3][0..15], t0 = 1024h + 4q : 256 B.
            const int q = st;
            float* base = out + ob + (size_t)(1024*h + 4*q) * 16;
            #pragma unroll
            for (int g = 0; g < 4; ++g) {
                // channels 4g..4g+3; Lc = (v(t0), v(t0+1), v(t0+2), v(t0+3))
                float4 L0 = *(const float4*)&tr[4*g + 0][2*q];
                float4 L1 = *(const float4*)&tr[4*g + 1][2*q];
                float4 L2 = *(const float4*)&tr[4*g + 2][2*q];
                float4 L3 = *(const float4*)&tr[4*g + 3][2*q];
                *(float4*)(base + 0*16 + 4*g) = make_float4(L0.x, L1.x, L2.x, L3.x);
                *(float4*)(base + 1*16 + 4*g) = make_float4(L0.y, L1.y, L2.y, L3.y);
                *(float4*)(base + 2*16 + 4*g) = make_float4(L0.z, L1.z, L2.z, L3.z);
                *(float4*)(base + 3*16 + 4*g) = make_float4(L0.w, L1.w, L2.w, L3.w);
            }
        }
        __syncthreads();
    }
}

extern "C" void kernel_launch(void* const* d_in, const int* in_sizes, int n_in,
                              void* d_out, int out_size, void* d_ws, size_t ws_size,
                              hipStream_t stream) {
    const float* x         = (const float*)d_in[0];
    const float* log_alpha = (const float*)d_in[1];
    const float* raw_tau   = (const float*)d_in[2];
    const float* raw_omega = (const float*)d_in[3];
    float* out = (float*)d_out;

    __half2* u_ws = (__half2*)d_ws;                       // 8192*2064*4 B = 67.6 MB
    float*   xT   = (float*)d_ws + XT_OFF_FLOATS;         // 16.8 MB at +80 MB

    k_tr <<<dim3(1024), dim3(256),  0, stream>>>(x, xT);
    k_fwd<<<dim3(1024), dim3(256),  0, stream>>>(xT, log_alpha, raw_tau, raw_omega, u_ws);
    k_inv<<<dim3(512),  dim3(1024), 0, stream>>>(u_ws, out);
}